// Round 6
// baseline (5276.789 us; speedup 1.0000x reference)
//
#include <hip/hip_runtime.h>
#include <cstdint>
#include <cstddef>

#define IN_DIM 256
#define HID    512
#define TSTEPS 8
#define ROWS   16      // batch rows per block
#define RPT    8       // rows per thread
#define NTHR   512
#define KC4    96      // OpenBLAS kc=384 boundary, float4 units (head loops)
#define KC8    48      // kc=384 boundary in 8-k units (layer 2/3 gemm)

// ---- weight pack: P[(i8*256 + j)*4 .. +3] (float4) =
//   { W[j][8i8..+3], W[j][8i8+4..+7], W[j+256][8i8..+3], W[j+256][8i8+4..+7] }
// One base address per (i8,thread); 4 dwordx4 at immediate offsets 0/16/32/48.
__global__ void wpack8(const float* __restrict__ W, float4* __restrict__ P, int K) {
  int idx = blockIdx.x * 256 + threadIdx.x;
  int i8 = idx >> 8, j = idx & 255;
  if (i8 >= (K >> 3)) return;
  const float4* wa = reinterpret_cast<const float4*>(W + (size_t)j * K + (i8 << 3));
  const float4* wb = reinterpret_cast<const float4*>(W + (size_t)(j + 256) * K + (i8 << 3));
  float4* o = P + (((size_t)i8 << 8) + j) * 4;
  o[0] = wa[0]; o[1] = wa[1]; o[2] = wb[0]; o[3] = wb[1];
}

// ---- v_fma_mix_f32: f32 fma with f16 src0 (lo or hi half). Exact equivalent of
// fmaf((float)h, w, acc) since f16->f32 conversion is exact and spikes are {0,1}.
__device__ __forceinline__ float mix_lo(unsigned s, float w, float acc) {
  float d;
  asm("v_fma_mix_f32 %0, %1, %2, %3 op_sel_hi:[1,0,0]"
      : "=v"(d) : "v"(s), "v"(w), "v"(acc));
  return d;
}
__device__ __forceinline__ float mix_hi(unsigned s, float w, float acc) {
  float d;
  asm("v_fma_mix_f32 %0, %1, %2, %3 op_sel:[1,0,0] op_sel_hi:[1,0,0]"
      : "=v"(d) : "v"(s), "v"(w), "v"(acc));
  return d;
}

// ---- f16-spike GEMM core (layers 2/3): ascending-k fp32 chain, BLAS GEBP order,
// bit-identical to the round-3-verified rounding. Per 8-k chunk: 8 broadcast
// ds_read_b128 (one per row), 4 coalesced dwordx4 (one base addr), 128 fma.
__device__ __forceinline__ void gemm_h(const unsigned short* __restrict__ sh, int rbase,
                                       const float4* __restrict__ P, int j1,
                                       int i8b, int i8e,
                                       float a0[RPT], float a1[RPT]) {
  for (int i8 = i8b; i8 < i8e; ++i8) {
    const float4* q = P + (((size_t)i8 << 8) + j1) * 4;
    float4 l0 = q[0], l1 = q[1], l2 = q[2], l3 = q[3];
    uint4 sv[RPT];
#pragma unroll
    for (int r = 0; r < RPT; ++r)
      sv[r] = *reinterpret_cast<const uint4*>(sh + ((rbase + r) << 9) + (i8 << 3));
#pragma unroll
    for (int r = 0; r < RPT; ++r) {
      float a = a0[r];
      a = mix_lo(sv[r].x, l0.x, a);  a = mix_hi(sv[r].x, l0.y, a);
      a = mix_lo(sv[r].y, l0.z, a);  a = mix_hi(sv[r].y, l0.w, a);
      a = mix_lo(sv[r].z, l1.x, a);  a = mix_hi(sv[r].z, l1.y, a);
      a = mix_lo(sv[r].w, l1.z, a);  a = mix_hi(sv[r].w, l1.w, a);
      a0[r] = a;
      float b = a1[r];
      b = mix_lo(sv[r].x, l2.x, b);  b = mix_hi(sv[r].x, l2.y, b);
      b = mix_lo(sv[r].y, l2.z, b);  b = mix_hi(sv[r].y, l2.w, b);
      b = mix_lo(sv[r].z, l3.x, b);  b = mix_hi(sv[r].z, l3.y, b);
      b = mix_lo(sv[r].w, l3.z, b);  b = mix_hi(sv[r].w, l3.w, b);
      a1[r] = b;
    }
  }
}

// ---- f32 obs GEMM core (layer 1, K=256): same chain order, obs f32 in LDS.
__device__ __forceinline__ void gemm_o(const float* __restrict__ so, int rbase,
                                       const float4* __restrict__ P, int j1,
                                       float a0[RPT], float a1[RPT]) {
  for (int i8 = 0; i8 < (IN_DIM >> 3); ++i8) {
    const float4* q = P + (((size_t)i8 << 8) + j1) * 4;
    float4 l0 = q[0], l1 = q[1], l2 = q[2], l3 = q[3];
#pragma unroll
    for (int r = 0; r < RPT; ++r) {
      const float4* sp = reinterpret_cast<const float4*>(so + ((rbase + r) << 8) + (i8 << 3));
      float4 s04 = sp[0], s48 = sp[1];
      float a = a0[r];
      a = fmaf(s04.x, l0.x, a); a = fmaf(s04.y, l0.y, a);
      a = fmaf(s04.z, l0.z, a); a = fmaf(s04.w, l0.w, a);
      a = fmaf(s48.x, l1.x, a); a = fmaf(s48.y, l1.y, a);
      a = fmaf(s48.z, l1.z, a); a = fmaf(s48.w, l1.w, a);
      a0[r] = a;
      float b = a1[r];
      b = fmaf(s04.x, l2.x, b); b = fmaf(s04.y, l2.y, b);
      b = fmaf(s04.z, l2.z, b); b = fmaf(s04.w, l2.w, b);
      b = fmaf(s48.x, l3.x, b); b = fmaf(s48.y, l3.y, b);
      b = fmaf(s48.z, l3.z, b); b = fmaf(s48.w, l3.w, b);
      a1[r] = b;
    }
  }
}

// (512,2): 128-VGPR budget, no spills (round-5 verified regime).
__launch_bounds__(NTHR, 2)
__global__ void snn_net(const float* __restrict__ obs,
                        const float4* __restrict__ pP1, const float* __restrict__ pb1_,
                        const float4* __restrict__ pP2, const float* __restrict__ pb2_,
                        const float4* __restrict__ pP3, const float* __restrict__ pb3_,
                        const float* __restrict__ paw, const float* __restrict__ pab,
                        const float4* __restrict__ vP1, const float* __restrict__ vb1_,
                        const float4* __restrict__ vP2, const float* __restrict__ vb2_,
                        const float4* __restrict__ vP3, const float* __restrict__ vb3_,
                        const float* __restrict__ vhw, const float* __restrict__ vhb,
                        const float* __restrict__ log_std,
                        float* __restrict__ out, int B) {
  // XCD split: policy on XCD 0-3, value on 4-7 (L2 holds one net's packs).
  const int bid = blockIdx.x;
  const int xcd = bid & 7;
  const int is_value = xcd >> 2;
  const int tile = (bid >> 3) * 4 + (xcd & 3);
  const float4* P1 = is_value ? vP1 : pP1;  const float* b1 = is_value ? vb1_ : pb1_;
  const float4* P2 = is_value ? vP2 : pP2;  const float* b2 = is_value ? vb2_ : pb2_;
  const float4* P3 = is_value ? vP3 : pP3;  const float* b3 = is_value ? vb3_ : pb3_;
  const float* Wh  = is_value ? vhw : paw;  const float* bh = is_value ? vhb : pab;

  // LDS 64KB: [A: s1 f16 16x512 =16K][B: s2 f16 =16K][c1 f32 16x512 =32K]
  // obs tile (16K f32) aliases A; head mean tile (32K f32) aliases A+B.
  __shared__ __align__(16) unsigned char lraw[65536];
  unsigned short* hA = (unsigned short*)lraw;
  unsigned short* hB = (unsigned short*)(lraw + 16384);
  float* c1l   = (float*)(lraw + 32768);
  float* obsT  = (float*)lraw;
  float* meanT = (float*)lraw;

  const int tid = threadIdx.x;
  const int r0 = tile * ROWS;
  const int j1 = tid & 255;
  const int rbase = (tid >> 8) * RPT;   // 0 or 8

  // ---- stage obs tile
  for (int e = tid; e < ROWS * IN_DIM; e += NTHR)
    obsT[e] = obs[(size_t)r0 * IN_DIM + e];
  __syncthreads();

  // ---- layer-1 currents (K=256, single BLAS panel; bias AFTER sum) -> LDS
  {
    float Sa[RPT], Sb[RPT];
#pragma unroll
    for (int r = 0; r < RPT; ++r) { Sa[r] = 0.f; Sb[r] = 0.f; }
    gemm_o(obsT, rbase, P1, j1, Sa, Sb);
    const float ba = b1[j1], bb = b1[j1 + 256];
    __syncthreads();   // all obs reads done; A region may be overwritten later
#pragma unroll
    for (int r = 0; r < RPT; ++r) {
      c1l[((rbase + r) << 9) + j1]       = __fadd_rn(Sa[r], ba);
      c1l[((rbase + r) << 9) + j1 + 256] = __fadd_rn(Sb[r], bb);
    }
    __syncthreads();
  }

  // ---- fp32 membranes; layer-3 spike counts packed 4b x 8 per u32
  float m1a[RPT], m1b[RPT], m2a[RPT], m2b[RPT], m3a[RPT], m3b[RPT];
  unsigned cnt_a = 0u, cnt_b = 0u;
#pragma unroll
  for (int r = 0; r < RPT; ++r) {
    m1a[r] = 0.f; m1b[r] = 0.f; m2a[r] = 0.f; m2b[r] = 0.f;
    m3a[r] = 0.f; m3b[r] = 0.f;
  }
  const float bias2a = b2[j1], bias2b = b2[j1 + 256];
  const float bias3a = b3[j1], bias3b = b3[j1 + 256];

  for (int t = 0; t < TSTEPS; ++t) {
    // LIF layer 1: m = RN(RN(0.95*m) + cur); spike f16 {0,1} exact -> A
#pragma unroll
    for (int r = 0; r < RPT; ++r) {
      float cura = c1l[((rbase + r) << 9) + j1];
      m1a[r] = __fadd_rn(__fmul_rn(0.95f, m1a[r]), cura);
      bool fa = m1a[r] > 1.0f;
      m1a[r] = __fsub_rn(m1a[r], fa ? 1.0f : 0.0f);
      hA[((rbase + r) << 9) + j1] = fa ? 0x3C00 : 0;
      float curb = c1l[((rbase + r) << 9) + j1 + 256];
      m1b[r] = __fadd_rn(__fmul_rn(0.95f, m1b[r]), curb);
      bool fb = m1b[r] > 1.0f;
      m1b[r] = __fsub_rn(m1b[r], fb ? 1.0f : 0.0f);
      hA[((rbase + r) << 9) + j1 + 256] = fb ? 0x3C00 : 0;
    }
    __syncthreads();   // A ready; also guarantees prev-t gemm3 B-reads are done

    // layer 2: two BLAS panels (kc=384), RN(S0+S1), then +bias
    float S0a[RPT], S0b[RPT], S1a[RPT], S1b[RPT];
#pragma unroll
    for (int r = 0; r < RPT; ++r) { S0a[r] = 0.f; S0b[r] = 0.f; S1a[r] = 0.f; S1b[r] = 0.f; }
    gemm_h(hA, rbase, P2, j1, 0, KC8, S0a, S0b);
    gemm_h(hA, rbase, P2, j1, KC8, HID >> 3, S1a, S1b);
#pragma unroll
    for (int r = 0; r < RPT; ++r) {
      float cura = __fadd_rn(__fadd_rn(S0a[r], S1a[r]), bias2a);
      m2a[r] = __fadd_rn(__fmul_rn(0.95f, m2a[r]), cura);
      bool fa = m2a[r] > 1.0f;
      m2a[r] = __fsub_rn(m2a[r], fa ? 1.0f : 0.0f);
      hB[((rbase + r) << 9) + j1] = fa ? 0x3C00 : 0;
      float curb = __fadd_rn(__fadd_rn(S0b[r], S1b[r]), bias2b);
      m2b[r] = __fadd_rn(__fmul_rn(0.95f, m2b[r]), curb);
      bool fb = m2b[r] > 1.0f;
      m2b[r] = __fsub_rn(m2b[r], fb ? 1.0f : 0.0f);
      hB[((rbase + r) << 9) + j1 + 256] = fb ? 0x3C00 : 0;
    }
    __syncthreads();   // B ready; all gemm2 A-reads complete

    // layer 3: same two-panel structure; packed spike counts
#pragma unroll
    for (int r = 0; r < RPT; ++r) { S0a[r] = 0.f; S0b[r] = 0.f; S1a[r] = 0.f; S1b[r] = 0.f; }
    gemm_h(hB, rbase, P3, j1, 0, KC8, S0a, S0b);
    gemm_h(hB, rbase, P3, j1, KC8, HID >> 3, S1a, S1b);
#pragma unroll
    for (int r = 0; r < RPT; ++r) {
      float cura = __fadd_rn(__fadd_rn(S0a[r], S1a[r]), bias3a);
      m3a[r] = __fadd_rn(__fmul_rn(0.95f, m3a[r]), cura);
      bool fa = m3a[r] > 1.0f;
      m3a[r] = __fsub_rn(m3a[r], fa ? 1.0f : 0.0f);
      cnt_a += fa ? (1u << (4 * r)) : 0u;
      float curb = __fadd_rn(__fadd_rn(S0b[r], S1b[r]), bias3b);
      m3b[r] = __fadd_rn(__fmul_rn(0.95f, m3b[r]), curb);
      bool fb = m3b[r] > 1.0f;
      m3b[r] = __fsub_rn(m3b[r], fb ? 1.0f : 0.0f);
      cnt_b += fb ? (1u << (4 * r)) : 0u;
    }
    // no barrier: next LIF1's A-write is fenced by the barrier after it.
  }
  __syncthreads();   // all gemm3 B-reads done before meanT overwrites A+B

  // ---- mean spikes (count/8 exact) into f32 tile
#pragma unroll
  for (int r = 0; r < RPT; ++r) {
    meanT[((rbase + r) << 9) + j1]       = (float)((cnt_a >> (4 * r)) & 15u) * 0.125f;
    meanT[((rbase + r) << 9) + j1 + 256] = (float)((cnt_b >> (4 * r)) & 15u) * 0.125f;
  }
  __syncthreads();

  // ---- heads (BLAS two-panel structure, kc=384)
  if (is_value == 0) {
    if (tid < ROWS * 6) {
      int r = tid / 6, k = tid % 6;
      const float* wr = Wh + (size_t)k * HID;
      float S0 = 0.f, S1 = 0.f;
      for (int i = 0; i < 4 * KC4; ++i)   S0 = fmaf(meanT[r * HID + i], wr[i], S0);
      for (int i = 4 * KC4; i < HID; ++i) S1 = fmaf(meanT[r * HID + i], wr[i], S1);
      out[(size_t)(r0 + r) * 6 + k] = __fadd_rn(__fadd_rn(S0, S1), bh[k]);
      out[(size_t)B * 6 + (size_t)(r0 + r) * 6 + k] = log_std[k];
    }
  } else {
    if (tid < ROWS) {
      int r = tid;
      float S0 = 0.f, S1 = 0.f;
      for (int i = 0; i < 4 * KC4; ++i)   S0 = fmaf(meanT[r * HID + i], Wh[i], S0);
      for (int i = 4 * KC4; i < HID; ++i) S1 = fmaf(meanT[r * HID + i], Wh[i], S1);
      out[(size_t)B * 12 + (size_t)(r0 + r)] = __fadd_rn(__fadd_rn(S0, S1), bh[0]);
    }
  }
}

// ---------------- fallback (round-3 kernel, proven; used if ws too small) --------
template<int PITCH4>
__device__ __forceinline__ void gemm_f32(const float* __restrict__ sl, int rbase,
                                         const float4* __restrict__ wra,
                                         const float4* __restrict__ wrb,
                                         int i4begin, int i4end,
                                         float a0[RPT], float a1[RPT]) {
  const float4* slv = reinterpret_cast<const float4*>(sl);
  for (int i4 = i4begin; i4 < i4end; ++i4) {
    float4 wa = wra[i4];
    float4 wb = wrb[i4];
#pragma unroll
    for (int r = 0; r < RPT; ++r) {
      float4 s = slv[(rbase + r) * PITCH4 + i4];
      a0[r] = fmaf(s.w, wa.w, fmaf(s.z, wa.z, fmaf(s.y, wa.y, fmaf(s.x, wa.x, a0[r]))));
      a1[r] = fmaf(s.w, wb.w, fmaf(s.z, wb.z, fmaf(s.y, wb.y, fmaf(s.x, wb.x, a1[r]))));
    }
  }
}

__launch_bounds__(NTHR, 2)
__global__ void snn_net_base(const float* __restrict__ obs,
                             const float* __restrict__ pW1, const float* __restrict__ pb1_,
                             const float* __restrict__ pW2, const float* __restrict__ pb2_,
                             const float* __restrict__ pW3, const float* __restrict__ pb3_,
                             const float* __restrict__ paw, const float* __restrict__ pab,
                             const float* __restrict__ vW1, const float* __restrict__ vb1_,
                             const float* __restrict__ vW2, const float* __restrict__ vb2_,
                             const float* __restrict__ vW3, const float* __restrict__ vb3_,
                             const float* __restrict__ vhw, const float* __restrict__ vhb,
                             const float* __restrict__ log_std,
                             float* __restrict__ out, int B) {
  const int is_value = blockIdx.y;
  const float* W1 = is_value ? vW1 : pW1;  const float* b1 = is_value ? vb1_ : pb1_;
  const float* W2 = is_value ? vW2 : pW2;  const float* b2 = is_value ? vb2_ : pb2_;
  const float* W3 = is_value ? vW3 : pW3;  const float* b3 = is_value ? vb3_ : pb3_;
  const float* Wh = is_value ? vhw : paw;  const float* bh = is_value ? vhb : pab;

  __shared__ float sl[ROWS * HID];
  const int tid = threadIdx.x;
  const int r0 = blockIdx.x * ROWS;
  const int j1 = tid & 255, j2 = j1 + 256;
  const int rbase = (tid >> 8) * RPT;

  for (int e = tid; e < ROWS * IN_DIM; e += NTHR)
    sl[e] = obs[(size_t)r0 * IN_DIM + e];
  __syncthreads();

  float c1a[RPT], c1b[RPT];
  {
    float Sa[RPT], Sb[RPT];
#pragma unroll
    for (int r = 0; r < RPT; ++r) { Sa[r] = 0.f; Sb[r] = 0.f; }
    gemm_f32<IN_DIM / 4>(sl, rbase,
        reinterpret_cast<const float4*>(W1 + (size_t)j1 * IN_DIM),
        reinterpret_cast<const float4*>(W1 + (size_t)j2 * IN_DIM),
        0, IN_DIM / 4, Sa, Sb);
    const float ba = b1[j1], bb = b1[j2];
#pragma unroll
    for (int r = 0; r < RPT; ++r) {
      c1a[r] = __fadd_rn(Sa[r], ba);
      c1b[r] = __fadd_rn(Sb[r], bb);
    }
  }
  __syncthreads();

  float m1a[RPT], m1b[RPT], m2a[RPT], m2b[RPT], m3a[RPT], m3b[RPT];
  float sca[RPT], scb[RPT];
#pragma unroll
  for (int r = 0; r < RPT; ++r) {
    m1a[r] = 0.f; m1b[r] = 0.f; m2a[r] = 0.f; m2b[r] = 0.f;
    m3a[r] = 0.f; m3b[r] = 0.f; sca[r] = 0.f; scb[r] = 0.f;
  }

  const float4* w2a = reinterpret_cast<const float4*>(W2 + (size_t)j1 * HID);
  const float4* w2b = reinterpret_cast<const float4*>(W2 + (size_t)j2 * HID);
  const float4* w3a = reinterpret_cast<const float4*>(W3 + (size_t)j1 * HID);
  const float4* w3b = reinterpret_cast<const float4*>(W3 + (size_t)j2 * HID);
  const float bias2a = b2[j1], bias2b = b2[j2];
  const float bias3a = b3[j1], bias3b = b3[j2];

  for (int t = 0; t < TSTEPS; ++t) {
#pragma unroll
    for (int r = 0; r < RPT; ++r) {
      m1a[r] = __fadd_rn(__fmul_rn(0.95f, m1a[r]), c1a[r]);
      float sa = (m1a[r] > 1.0f) ? 1.0f : 0.0f;
      m1a[r] = __fsub_rn(m1a[r], sa);
      sl[(rbase + r) * HID + j1] = sa;
      m1b[r] = __fadd_rn(__fmul_rn(0.95f, m1b[r]), c1b[r]);
      float sb = (m1b[r] > 1.0f) ? 1.0f : 0.0f;
      m1b[r] = __fsub_rn(m1b[r], sb);
      sl[(rbase + r) * HID + j2] = sb;
    }
    __syncthreads();

    float S0a[RPT], S0b[RPT], S1a[RPT], S1b[RPT];
#pragma unroll
    for (int r = 0; r < RPT; ++r) { S0a[r] = 0.f; S0b[r] = 0.f; S1a[r] = 0.f; S1b[r] = 0.f; }
    gemm_f32<HID / 4>(sl, rbase, w2a, w2b, 0, KC4, S0a, S0b);
    gemm_f32<HID / 4>(sl, rbase, w2a, w2b, KC4, HID / 4, S1a, S1b);
    __syncthreads();
#pragma unroll
    for (int r = 0; r < RPT; ++r) {
      float cura = __fadd_rn(__fadd_rn(S0a[r], S1a[r]), bias2a);
      float curb = __fadd_rn(__fadd_rn(S0b[r], S1b[r]), bias2b);
      m2a[r] = __fadd_rn(__fmul_rn(0.95f, m2a[r]), cura);
      float sa = (m2a[r] > 1.0f) ? 1.0f : 0.0f;
      m2a[r] = __fsub_rn(m2a[r], sa);
      sl[(rbase + r) * HID + j1] = sa;
      m2b[r] = __fadd_rn(__fmul_rn(0.95f, m2b[r]), curb);
      float sb = (m2b[r] > 1.0f) ? 1.0f : 0.0f;
      m2b[r] = __fsub_rn(m2b[r], sb);
      sl[(rbase + r) * HID + j2] = sb;
    }
    __syncthreads();

#pragma unroll
    for (int r = 0; r < RPT; ++r) { S0a[r] = 0.f; S0b[r] = 0.f; S1a[r] = 0.f; S1b[r] = 0.f; }
    gemm_f32<HID / 4>(sl, rbase, w3a, w3b, 0, KC4, S0a, S0b);
    gemm_f32<HID / 4>(sl, rbase, w3a, w3b, KC4, HID / 4, S1a, S1b);
    __syncthreads();
#pragma unroll
    for (int r = 0; r < RPT; ++r) {
      float cura = __fadd_rn(__fadd_rn(S0a[r], S1a[r]), bias3a);
      float curb = __fadd_rn(__fadd_rn(S0b[r], S1b[r]), bias3b);
      m3a[r] = __fadd_rn(__fmul_rn(0.95f, m3a[r]), cura);
      float sa = (m3a[r] > 1.0f) ? 1.0f : 0.0f;
      m3a[r] = __fsub_rn(m3a[r], sa);
      sca[r] = __fadd_rn(sca[r], sa);
      m3b[r] = __fadd_rn(__fmul_rn(0.95f, m3b[r]), curb);
      float sb = (m3b[r] > 1.0f) ? 1.0f : 0.0f;
      m3b[r] = __fsub_rn(m3b[r], sb);
      scb[r] = __fadd_rn(scb[r], sb);
    }
  }

#pragma unroll
  for (int r = 0; r < RPT; ++r) {
    sl[(rbase + r) * HID + j1] = sca[r] * 0.125f;
    sl[(rbase + r) * HID + j2] = scb[r] * 0.125f;
  }
  __syncthreads();

  if (is_value == 0) {
    if (tid < ROWS * 6) {
      int r = tid / 6, k = tid % 6;
      const float* wr = Wh + (size_t)k * HID;
      float S0 = 0.f, S1 = 0.f;
      for (int i = 0; i < 4 * KC4; ++i)   S0 = fmaf(sl[r * HID + i], wr[i], S0);
      for (int i = 4 * KC4; i < HID; ++i) S1 = fmaf(sl[r * HID + i], wr[i], S1);
      out[(size_t)(r0 + r) * 6 + k] = __fadd_rn(__fadd_rn(S0, S1), bh[k]);
      out[(size_t)B * 6 + (size_t)(r0 + r) * 6 + k] = log_std[k];
    }
  } else {
    if (tid < ROWS) {
      int r = tid;
      float S0 = 0.f, S1 = 0.f;
      for (int i = 0; i < 4 * KC4; ++i)   S0 = fmaf(sl[r * HID + i], Wh[i], S0);
      for (int i = 4 * KC4; i < HID; ++i) S1 = fmaf(sl[r * HID + i], Wh[i], S1);
      out[(size_t)B * 12 + (size_t)(r0 + r)] = __fadd_rn(__fadd_rn(S0, S1), bh[0]);
    }
  }
}

extern "C" void kernel_launch(void* const* d_in, const int* in_sizes, int n_in,
                              void* d_out, int out_size, void* d_ws, size_t ws_size,
                              hipStream_t stream) {
  const float* obs = (const float*)d_in[0];
  const float* pw1 = (const float*)d_in[1];  const float* pb1 = (const float*)d_in[2];
  const float* pw2 = (const float*)d_in[3];  const float* pb2 = (const float*)d_in[4];
  const float* pw3 = (const float*)d_in[5];  const float* pb3 = (const float*)d_in[6];
  const float* aw  = (const float*)d_in[7];  const float* ab  = (const float*)d_in[8];
  const float* vw1 = (const float*)d_in[9];  const float* vb1 = (const float*)d_in[10];
  const float* vw2 = (const float*)d_in[11]; const float* vb2 = (const float*)d_in[12];
  const float* vw3 = (const float*)d_in[13]; const float* vb3 = (const float*)d_in[14];
  const float* hw  = (const float*)d_in[15]; const float* hb  = (const float*)d_in[16];
  const float* lsd = (const float*)d_in[17];
  float* out = (float*)d_out;

  const int B  = in_sizes[0] / IN_DIM;
  const int nb = B / ROWS;

  const size_t need = (size_t)(IN_DIM * HID + 2 * HID * HID) * 2 * sizeof(float);
  if (ws_size >= need && (nb & 3) == 0) {
    float* w = (float*)d_ws;
    float4* pP1 = (float4*)(w);
    float4* pP2 = (float4*)(w + 131072);
    float4* pP3 = (float4*)(w + 393216);
    float4* vP1 = (float4*)(w + 655360);
    float4* vP2 = (float4*)(w + 786432);
    float4* vP3 = (float4*)(w + 1048576);
    wpack8<<<IN_DIM / 8, 256, 0, stream>>>(pw1, pP1, IN_DIM);
    wpack8<<<HID / 8,    256, 0, stream>>>(pw2, pP2, HID);
    wpack8<<<HID / 8,    256, 0, stream>>>(pw3, pP3, HID);
    wpack8<<<IN_DIM / 8, 256, 0, stream>>>(vw1, vP1, IN_DIM);
    wpack8<<<HID / 8,    256, 0, stream>>>(vw2, vP2, HID);
    wpack8<<<HID / 8,    256, 0, stream>>>(vw3, vP3, HID);
    snn_net<<<2 * nb, NTHR, 0, stream>>>(obs,
        pP1, pb1, pP2, pb2, pP3, pb3, aw, ab,
        vP1, vb1, vP2, vb2, vP3, vb3, hw, hb,
        lsd, out, B);
  } else {
    dim3 grid(nb, 2);
    snn_net_base<<<grid, NTHR, 0, stream>>>(obs,
        pw1, pb1, pw2, pb2, pw3, pb3, aw, ab,
        vw1, vb1, vw2, vb2, vw3, vb3, hw, hb,
        lsd, out, B);
  }
}

// Round 7
// 4515.094 us; speedup vs baseline: 1.1687x; 1.1687x over previous
//
#include <hip/hip_runtime.h>
#include <cstdint>
#include <cstddef>

#define IN_DIM 256
#define HID    512
#define TSTEPS 8
#define ROWS   16      // batch rows per block
#define NTHR   512
#define KC4    96      // OpenBLAS kc=384 boundary, float4 units (head loops)

// ---------------- weight transpose: in[R][C] -> outT[C][R] (round-4 proven) ----
__global__ void wtrans(const float* __restrict__ in, float* __restrict__ outT,
                       int R, int C) {
  __shared__ float tile[32][33];
  const int c0 = blockIdx.x * 32, r0 = blockIdx.y * 32;
  const int tx = threadIdx.x & 31, ty = threadIdx.x >> 5;   // 32x8
#pragma unroll
  for (int i = 0; i < 32; i += 8)
    tile[ty + i][tx] = in[(size_t)(r0 + ty + i) * C + (c0 + tx)];
  __syncthreads();
#pragma unroll
  for (int i = 0; i < 32; i += 8)
    outT[(size_t)(c0 + ty + i) * R + (r0 + tx)] = tile[tx][ty + i];
}

// ---------------- sparse-spike SNN kernel ----------------
// Thread layout: j1 = tid&127 -> cols {j1, j1+128, j1+256, j1+384};
// g = tid>>7 -> rows {4g..4g+3}. Spikes live as bitmasks (wave-uniform);
// zero-skip is BIT-EXACT: fma(0,w,acc)==acc, fma(1,w,acc)==fadd(acc,w).
__launch_bounds__(NTHR, 2)
__global__ void snn_net(const float* __restrict__ obs,
                        const float* __restrict__ pT1, const float* __restrict__ pb1_,
                        const float* __restrict__ pT2, const float* __restrict__ pb2_,
                        const float* __restrict__ pT3, const float* __restrict__ pb3_,
                        const float* __restrict__ paw, const float* __restrict__ pab,
                        const float* __restrict__ vT1, const float* __restrict__ vb1_,
                        const float* __restrict__ vT2, const float* __restrict__ vb2_,
                        const float* __restrict__ vT3, const float* __restrict__ vb3_,
                        const float* __restrict__ vhw, const float* __restrict__ vhb,
                        const float* __restrict__ log_std,
                        float* __restrict__ out, int B) {
  // XCD split: policy on XCD 0-3, value on 4-7.
  const int bid = blockIdx.x;
  const int xcd = bid & 7;
  const int is_value = xcd >> 2;
  const int tile = (bid >> 3) * 4 + (xcd & 3);
  const float* W1T = is_value ? vT1 : pT1;  const float* b1 = is_value ? vb1_ : pb1_;
  const float* W2T = is_value ? vT2 : pT2;  const float* b2 = is_value ? vb2_ : pb2_;
  const float* W3T = is_value ? vT3 : pT3;  const float* b3 = is_value ? vb3_ : pb3_;
  const float* Wh  = is_value ? vhw : paw;  const float* bh = is_value ? vhb : pab;

  // LDS: [0,32K): obs tile (16K) then mean tile (32K). [32K,33K): maskA. [33K,34K): maskB.
  __shared__ __align__(16) unsigned char lraw[34816];
  float* obsT  = (float*)lraw;
  float* meanT = (float*)lraw;
  unsigned* maskA = (unsigned*)(lraw + 32768);   // [16 rows][16 words]
  unsigned* maskB = maskA + 256;

  const int tid  = threadIdx.x;
  const int lane = tid & 63;
  const int wid  = tid >> 6;
  const int j1   = tid & 127;
  const int g    = tid >> 7;          // row group: rows 4g..4g+3
  const int whalf = (wid & 1) << 1;   // word offset within colblock: 0 or 2
  const int r0 = tile * ROWS;

  // ---- stage obs tile
  for (int e = tid; e < ROWS * IN_DIM; e += NTHR)
    obsT[e] = obs[(size_t)r0 * IN_DIM + e];
  __syncthreads();

  // ---- layer-1 currents (dense, K=256 single BLAS panel, bias AFTER sum)
  float c1v[4][4];
#pragma unroll
  for (int rr = 0; rr < 4; ++rr)
#pragma unroll
    for (int c = 0; c < 4; ++c) c1v[rr][c] = 0.f;

  for (int i4 = 0; i4 < IN_DIM / 4; ++i4) {
    float w[4][4];  // [kk][c]
#pragma unroll
    for (int kk = 0; kk < 4; ++kk) {
      const float* wr = W1T + ((size_t)(i4 * 4 + kk) << 9);
      w[kk][0] = wr[j1];       w[kk][1] = wr[j1 + 128];
      w[kk][2] = wr[j1 + 256]; w[kk][3] = wr[j1 + 384];
    }
#pragma unroll
    for (int rr = 0; rr < 4; ++rr) {
      float4 o = *reinterpret_cast<const float4*>(&obsT[(4 * g + rr) * IN_DIM + i4 * 4]);
#pragma unroll
      for (int c = 0; c < 4; ++c) {
        float a = c1v[rr][c];
        a = fmaf(o.x, w[0][c], a);
        a = fmaf(o.y, w[1][c], a);
        a = fmaf(o.z, w[2][c], a);
        a = fmaf(o.w, w[3][c], a);
        c1v[rr][c] = a;
      }
    }
  }
  {
    float bb[4] = { b1[j1], b1[j1 + 128], b1[j1 + 256], b1[j1 + 384] };
#pragma unroll
    for (int rr = 0; rr < 4; ++rr)
#pragma unroll
      for (int c = 0; c < 4; ++c)
        c1v[rr][c] = __fadd_rn(c1v[rr][c], bb[c]);
  }
  __syncthreads();  // obs reads done; offset-0 region reusable later

  // ---- state
  float m1[4][4], m2[4][4], m3[4][4];
#pragma unroll
  for (int rr = 0; rr < 4; ++rr)
#pragma unroll
    for (int c = 0; c < 4; ++c) { m1[rr][c] = 0.f; m2[rr][c] = 0.f; m3[rr][c] = 0.f; }
  unsigned long long cnt = 0ull;

  const float bias2[4] = { b2[j1], b2[j1 + 128], b2[j1 + 256], b2[j1 + 384] };
  const float bias3[4] = { b3[j1], b3[j1 + 128], b3[j1 + 256], b3[j1 + 384] };

  // scalar zero-skip over one 32-bit mask word (ascending k; bit-exact)
  auto proc = [&](unsigned mword, int kbase, const float* __restrict__ WT,
                  float* __restrict__ A) {
    unsigned m = (unsigned)__builtin_amdgcn_readfirstlane((int)mword);
    while (m) {
      int kb = __builtin_ctz(m);
      m &= m - 1;
      const float* wr = WT + ((size_t)(kbase + kb) << 9);
      float w0 = wr[j1], w1 = wr[j1 + 128], w2 = wr[j1 + 256], w3 = wr[j1 + 384];
      A[0] = __fadd_rn(A[0], w0);
      A[1] = __fadd_rn(A[1], w1);
      A[2] = __fadd_rn(A[2], w2);
      A[3] = __fadd_rn(A[3], w3);
    }
  };

  for (int t = 0; t < TSTEPS; ++t) {
    // ---- LIF layer 1: m = RN(RN(0.95*m)+cur); spikes -> ballots -> maskA
#pragma unroll
    for (int rr = 0; rr < 4; ++rr) {
      bool sp[4];
#pragma unroll
      for (int c = 0; c < 4; ++c) {
        m1[rr][c] = __fadd_rn(__fmul_rn(0.95f, m1[rr][c]), c1v[rr][c]);
        bool f = m1[rr][c] > 1.0f;
        m1[rr][c] = __fsub_rn(m1[rr][c], f ? 1.0f : 0.0f);
        sp[c] = f;
      }
#pragma unroll
      for (int c = 0; c < 4; ++c) {
        unsigned long long bal = __ballot(sp[c]);
        if (lane == 0)
          *(unsigned long long*)&maskA[(4 * g + rr) * 16 + 4 * c + whalf] = bal;
      }
    }
    __syncthreads();   // maskA ready; prior-t gemm3 maskB reads done

    // ---- layer 2 (sparse): words 0-11 -> S0 panel, 12-15 -> S1 (kc=384)
#pragma unroll
    for (int rr = 0; rr < 4; ++rr) {
      const int r = 4 * g + rr;
      const uint4* mr = reinterpret_cast<const uint4*>(&maskA[r * 16]);
      uint4 q0 = mr[0], q1 = mr[1], q2 = mr[2], q3 = mr[3];
      float A0[4] = {0.f, 0.f, 0.f, 0.f}, A1[4] = {0.f, 0.f, 0.f, 0.f};
      proc(q0.x,   0, W2T, A0); proc(q0.y,  32, W2T, A0);
      proc(q0.z,  64, W2T, A0); proc(q0.w,  96, W2T, A0);
      proc(q1.x, 128, W2T, A0); proc(q1.y, 160, W2T, A0);
      proc(q1.z, 192, W2T, A0); proc(q1.w, 224, W2T, A0);
      proc(q2.x, 256, W2T, A0); proc(q2.y, 288, W2T, A0);
      proc(q2.z, 320, W2T, A0); proc(q2.w, 352, W2T, A0);
      proc(q3.x, 384, W2T, A1); proc(q3.y, 416, W2T, A1);
      proc(q3.z, 448, W2T, A1); proc(q3.w, 480, W2T, A1);
      bool sp[4];
#pragma unroll
      for (int c = 0; c < 4; ++c) {
        float cur = __fadd_rn(__fadd_rn(A0[c], A1[c]), bias2[c]);
        m2[rr][c] = __fadd_rn(__fmul_rn(0.95f, m2[rr][c]), cur);
        bool f = m2[rr][c] > 1.0f;
        m2[rr][c] = __fsub_rn(m2[rr][c], f ? 1.0f : 0.0f);
        sp[c] = f;
      }
#pragma unroll
      for (int c = 0; c < 4; ++c) {
        unsigned long long bal = __ballot(sp[c]);
        if (lane == 0)
          *(unsigned long long*)&maskB[r * 16 + 4 * c + whalf] = bal;
      }
    }
    __syncthreads();   // maskB ready; gemm2 maskA reads done

    // ---- layer 3 (sparse): same structure; spikes -> packed counts
#pragma unroll
    for (int rr = 0; rr < 4; ++rr) {
      const int r = 4 * g + rr;
      const uint4* mr = reinterpret_cast<const uint4*>(&maskB[r * 16]);
      uint4 q0 = mr[0], q1 = mr[1], q2 = mr[2], q3 = mr[3];
      float A0[4] = {0.f, 0.f, 0.f, 0.f}, A1[4] = {0.f, 0.f, 0.f, 0.f};
      proc(q0.x,   0, W3T, A0); proc(q0.y,  32, W3T, A0);
      proc(q0.z,  64, W3T, A0); proc(q0.w,  96, W3T, A0);
      proc(q1.x, 128, W3T, A0); proc(q1.y, 160, W3T, A0);
      proc(q1.z, 192, W3T, A0); proc(q1.w, 224, W3T, A0);
      proc(q2.x, 256, W3T, A0); proc(q2.y, 288, W3T, A0);
      proc(q2.z, 320, W3T, A0); proc(q2.w, 352, W3T, A0);
      proc(q3.x, 384, W3T, A1); proc(q3.y, 416, W3T, A1);
      proc(q3.z, 448, W3T, A1); proc(q3.w, 480, W3T, A1);
#pragma unroll
      for (int c = 0; c < 4; ++c) {
        float cur = __fadd_rn(__fadd_rn(A0[c], A1[c]), bias3[c]);
        m3[rr][c] = __fadd_rn(__fmul_rn(0.95f, m3[rr][c]), cur);
        bool f = m3[rr][c] > 1.0f;
        m3[rr][c] = __fsub_rn(m3[rr][c], f ? 1.0f : 0.0f);
        cnt += f ? (1ull << (4 * (rr * 4 + c))) : 0ull;
      }
    }
    // no barrier: next LIF1 writes maskA only, fenced by the barrier after it.
  }
  __syncthreads();   // everyone out of the t-loop before meanT overwrites LDS

  // ---- mean spikes (count/8 exact) into f32 tile
#pragma unroll
  for (int rr = 0; rr < 4; ++rr)
#pragma unroll
    for (int c = 0; c < 4; ++c)
      meanT[(4 * g + rr) * HID + j1 + 128 * c] =
          (float)((cnt >> (4 * (rr * 4 + c))) & 15ull) * 0.125f;
  __syncthreads();

  // ---- heads (BLAS two-panel structure, kc=384)
  if (is_value == 0) {
    if (tid < ROWS * 6) {
      int r = tid / 6, k = tid % 6;
      const float* wr = Wh + (size_t)k * HID;
      float S0 = 0.f, S1 = 0.f;
      for (int i = 0; i < 4 * KC4; ++i)   S0 = fmaf(meanT[r * HID + i], wr[i], S0);
      for (int i = 4 * KC4; i < HID; ++i) S1 = fmaf(meanT[r * HID + i], wr[i], S1);
      out[(size_t)(r0 + r) * 6 + k] = __fadd_rn(__fadd_rn(S0, S1), bh[k]);
      out[(size_t)B * 6 + (size_t)(r0 + r) * 6 + k] = log_std[k];
    }
  } else {
    if (tid < ROWS) {
      int r = tid;
      float S0 = 0.f, S1 = 0.f;
      for (int i = 0; i < 4 * KC4; ++i)   S0 = fmaf(meanT[r * HID + i], Wh[i], S0);
      for (int i = 4 * KC4; i < HID; ++i) S1 = fmaf(meanT[r * HID + i], Wh[i], S1);
      out[(size_t)B * 12 + (size_t)(r0 + r)] = __fadd_rn(__fadd_rn(S0, S1), bh[0]);
    }
  }
}

// ---------------- fallback (round-3 kernel, proven; used if ws too small) --------
#define RPT 8
template<int PITCH4>
__device__ __forceinline__ void gemm_f32(const float* __restrict__ sl, int rbase,
                                         const float4* __restrict__ wra,
                                         const float4* __restrict__ wrb,
                                         int i4begin, int i4end,
                                         float a0[RPT], float a1[RPT]) {
  const float4* slv = reinterpret_cast<const float4*>(sl);
  for (int i4 = i4begin; i4 < i4end; ++i4) {
    float4 wa = wra[i4];
    float4 wb = wrb[i4];
#pragma unroll
    for (int r = 0; r < RPT; ++r) {
      float4 s = slv[(rbase + r) * PITCH4 + i4];
      a0[r] = fmaf(s.w, wa.w, fmaf(s.z, wa.z, fmaf(s.y, wa.y, fmaf(s.x, wa.x, a0[r]))));
      a1[r] = fmaf(s.w, wb.w, fmaf(s.z, wb.z, fmaf(s.y, wb.y, fmaf(s.x, wb.x, a1[r]))));
    }
  }
}

__launch_bounds__(NTHR, 2)
__global__ void snn_net_base(const float* __restrict__ obs,
                             const float* __restrict__ pW1, const float* __restrict__ pb1_,
                             const float* __restrict__ pW2, const float* __restrict__ pb2_,
                             const float* __restrict__ pW3, const float* __restrict__ pb3_,
                             const float* __restrict__ paw, const float* __restrict__ pab,
                             const float* __restrict__ vW1, const float* __restrict__ vb1_,
                             const float* __restrict__ vW2, const float* __restrict__ vb2_,
                             const float* __restrict__ vW3, const float* __restrict__ vb3_,
                             const float* __restrict__ vhw, const float* __restrict__ vhb,
                             const float* __restrict__ log_std,
                             float* __restrict__ out, int B) {
  const int is_value = blockIdx.y;
  const float* W1 = is_value ? vW1 : pW1;  const float* b1 = is_value ? vb1_ : pb1_;
  const float* W2 = is_value ? vW2 : pW2;  const float* b2 = is_value ? vb2_ : pb2_;
  const float* W3 = is_value ? vW3 : pW3;  const float* b3 = is_value ? vb3_ : pb3_;
  const float* Wh = is_value ? vhw : paw;  const float* bh = is_value ? vhb : pab;

  __shared__ float sl[ROWS * HID];
  const int tid = threadIdx.x;
  const int r0 = blockIdx.x * ROWS;
  const int j1 = tid & 255, j2 = j1 + 256;
  const int rbase = (tid >> 8) * RPT;

  for (int e = tid; e < ROWS * IN_DIM; e += NTHR)
    sl[e] = obs[(size_t)r0 * IN_DIM + e];
  __syncthreads();

  float c1a[RPT], c1b[RPT];
  {
    float Sa[RPT], Sb[RPT];
#pragma unroll
    for (int r = 0; r < RPT; ++r) { Sa[r] = 0.f; Sb[r] = 0.f; }
    gemm_f32<IN_DIM / 4>(sl, rbase,
        reinterpret_cast<const float4*>(W1 + (size_t)j1 * IN_DIM),
        reinterpret_cast<const float4*>(W1 + (size_t)j2 * IN_DIM),
        0, IN_DIM / 4, Sa, Sb);
    const float ba = b1[j1], bb = b1[j2];
#pragma unroll
    for (int r = 0; r < RPT; ++r) {
      c1a[r] = __fadd_rn(Sa[r], ba);
      c1b[r] = __fadd_rn(Sb[r], bb);
    }
  }
  __syncthreads();

  float m1a[RPT], m1b[RPT], m2a[RPT], m2b[RPT], m3a[RPT], m3b[RPT];
  float sca[RPT], scb[RPT];
#pragma unroll
  for (int r = 0; r < RPT; ++r) {
    m1a[r] = 0.f; m1b[r] = 0.f; m2a[r] = 0.f; m2b[r] = 0.f;
    m3a[r] = 0.f; m3b[r] = 0.f; sca[r] = 0.f; scb[r] = 0.f;
  }

  const float4* w2a = reinterpret_cast<const float4*>(W2 + (size_t)j1 * HID);
  const float4* w2b = reinterpret_cast<const float4*>(W2 + (size_t)j2 * HID);
  const float4* w3a = reinterpret_cast<const float4*>(W3 + (size_t)j1 * HID);
  const float4* w3b = reinterpret_cast<const float4*>(W3 + (size_t)j2 * HID);
  const float bias2a = b2[j1], bias2b = b2[j2];
  const float bias3a = b3[j1], bias3b = b3[j2];

  for (int t = 0; t < TSTEPS; ++t) {
#pragma unroll
    for (int r = 0; r < RPT; ++r) {
      m1a[r] = __fadd_rn(__fmul_rn(0.95f, m1a[r]), c1a[r]);
      float sa = (m1a[r] > 1.0f) ? 1.0f : 0.0f;
      m1a[r] = __fsub_rn(m1a[r], sa);
      sl[(rbase + r) * HID + j1] = sa;
      m1b[r] = __fadd_rn(__fmul_rn(0.95f, m1b[r]), c1b[r]);
      float sb = (m1b[r] > 1.0f) ? 1.0f : 0.0f;
      m1b[r] = __fsub_rn(m1b[r], sb);
      sl[(rbase + r) * HID + j2] = sb;
    }
    __syncthreads();

    float S0a[RPT], S0b[RPT], S1a[RPT], S1b[RPT];
#pragma unroll
    for (int r = 0; r < RPT; ++r) { S0a[r] = 0.f; S0b[r] = 0.f; S1a[r] = 0.f; S1b[r] = 0.f; }
    gemm_f32<HID / 4>(sl, rbase, w2a, w2b, 0, KC4, S0a, S0b);
    gemm_f32<HID / 4>(sl, rbase, w2a, w2b, KC4, HID / 4, S1a, S1b);
    __syncthreads();
#pragma unroll
    for (int r = 0; r < RPT; ++r) {
      float cura = __fadd_rn(__fadd_rn(S0a[r], S1a[r]), bias2a);
      float curb = __fadd_rn(__fadd_rn(S0b[r], S1b[r]), bias2b);
      m2a[r] = __fadd_rn(__fmul_rn(0.95f, m2a[r]), cura);
      float sa = (m2a[r] > 1.0f) ? 1.0f : 0.0f;
      m2a[r] = __fsub_rn(m2a[r], sa);
      sl[(rbase + r) * HID + j1] = sa;
      m2b[r] = __fadd_rn(__fmul_rn(0.95f, m2b[r]), curb);
      float sb = (m2b[r] > 1.0f) ? 1.0f : 0.0f;
      m2b[r] = __fsub_rn(m2b[r], sb);
      sl[(rbase + r) * HID + j2] = sb;
    }
    __syncthreads();

#pragma unroll
    for (int r = 0; r < RPT; ++r) { S0a[r] = 0.f; S0b[r] = 0.f; S1a[r] = 0.f; S1b[r] = 0.f; }
    gemm_f32<HID / 4>(sl, rbase, w3a, w3b, 0, KC4, S0a, S0b);
    gemm_f32<HID / 4>(sl, rbase, w3a, w3b, KC4, HID / 4, S1a, S1b);
    __syncthreads();
#pragma unroll
    for (int r = 0; r < RPT; ++r) {
      float cura = __fadd_rn(__fadd_rn(S0a[r], S1a[r]), bias3a);
      float curb = __fadd_rn(__fadd_rn(S0b[r], S1b[r]), bias3b);
      m3a[r] = __fadd_rn(__fmul_rn(0.95f, m3a[r]), cura);
      float sa = (m3a[r] > 1.0f) ? 1.0f : 0.0f;
      m3a[r] = __fsub_rn(m3a[r], sa);
      sca[r] = __fadd_rn(sca[r], sa);
      m3b[r] = __fadd_rn(__fmul_rn(0.95f, m3b[r]), curb);
      float sb = (m3b[r] > 1.0f) ? 1.0f : 0.0f;
      m3b[r] = __fsub_rn(m3b[r], sb);
      scb[r] = __fadd_rn(scb[r], sb);
    }
  }

#pragma unroll
  for (int r = 0; r < RPT; ++r) {
    sl[(rbase + r) * HID + j1] = sca[r] * 0.125f;
    sl[(rbase + r) * HID + j2] = scb[r] * 0.125f;
  }
  __syncthreads();

  if (is_value == 0) {
    if (tid < ROWS * 6) {
      int r = tid / 6, k = tid % 6;
      const float* wr = Wh + (size_t)k * HID;
      float S0 = 0.f, S1 = 0.f;
      for (int i = 0; i < 4 * KC4; ++i)   S0 = fmaf(sl[r * HID + i], wr[i], S0);
      for (int i = 4 * KC4; i < HID; ++i) S1 = fmaf(sl[r * HID + i], wr[i], S1);
      out[(size_t)(r0 + r) * 6 + k] = __fadd_rn(__fadd_rn(S0, S1), bh[k]);
      out[(size_t)B * 6 + (size_t)(r0 + r) * 6 + k] = log_std[k];
    }
  } else {
    if (tid < ROWS) {
      int r = tid;
      float S0 = 0.f, S1 = 0.f;
      for (int i = 0; i < 4 * KC4; ++i)   S0 = fmaf(sl[r * HID + i], Wh[i], S0);
      for (int i = 4 * KC4; i < HID; ++i) S1 = fmaf(sl[r * HID + i], Wh[i], S1);
      out[(size_t)B * 12 + (size_t)(r0 + r)] = __fadd_rn(__fadd_rn(S0, S1), bh[0]);
    }
  }
}

extern "C" void kernel_launch(void* const* d_in, const int* in_sizes, int n_in,
                              void* d_out, int out_size, void* d_ws, size_t ws_size,
                              hipStream_t stream) {
  const float* obs = (const float*)d_in[0];
  const float* pw1 = (const float*)d_in[1];  const float* pb1 = (const float*)d_in[2];
  const float* pw2 = (const float*)d_in[3];  const float* pb2 = (const float*)d_in[4];
  const float* pw3 = (const float*)d_in[5];  const float* pb3 = (const float*)d_in[6];
  const float* aw  = (const float*)d_in[7];  const float* ab  = (const float*)d_in[8];
  const float* vw1 = (const float*)d_in[9];  const float* vb1 = (const float*)d_in[10];
  const float* vw2 = (const float*)d_in[11]; const float* vb2 = (const float*)d_in[12];
  const float* vw3 = (const float*)d_in[13]; const float* vb3 = (const float*)d_in[14];
  const float* hw  = (const float*)d_in[15]; const float* hb  = (const float*)d_in[16];
  const float* lsd = (const float*)d_in[17];
  float* out = (float*)d_out;

  const int B  = in_sizes[0] / IN_DIM;
  const int nb = B / ROWS;

  const size_t need = (size_t)(IN_DIM * HID + 2 * HID * HID) * 2 * sizeof(float);
  if (ws_size >= need && (nb & 3) == 0) {
    float* w = (float*)d_ws;
    float* pT1 = w;               // WT[k][j]: [256][512]
    float* pT2 = w + 131072;      // [512][512]
    float* pT3 = w + 393216;
    float* vT1 = w + 655360;
    float* vT2 = w + 786432;
    float* vT3 = w + 1048576;
    wtrans<<<dim3(IN_DIM / 32, HID / 32), 256, 0, stream>>>(pw1, pT1, HID, IN_DIM);
    wtrans<<<dim3(HID / 32, HID / 32), 256, 0, stream>>>(pw2, pT2, HID, HID);
    wtrans<<<dim3(HID / 32, HID / 32), 256, 0, stream>>>(pw3, pT3, HID, HID);
    wtrans<<<dim3(IN_DIM / 32, HID / 32), 256, 0, stream>>>(vw1, vT1, HID, IN_DIM);
    wtrans<<<dim3(HID / 32, HID / 32), 256, 0, stream>>>(vw2, vT2, HID, HID);
    wtrans<<<dim3(HID / 32, HID / 32), 256, 0, stream>>>(vw3, vT3, HID, HID);
    snn_net<<<2 * nb, NTHR, 0, stream>>>(obs,
        pT1, pb1, pT2, pb2, pT3, pb3, aw, ab,
        vT1, vb1, vT2, vb2, vT3, vb3, hw, hb,
        lsd, out, B);
  } else {
    dim3 grid(nb, 2);
    snn_net_base<<<grid, NTHR, 0, stream>>>(obs,
        pw1, pb1, pw2, pb2, pw3, pb3, aw, ab,
        vw1, vb1, vw2, vb2, vw3, vb3, hw, hb,
        lsd, out, B);
  }
}

// Round 8
// 4282.346 us; speedup vs baseline: 1.2322x; 1.0544x over previous
//
#include <hip/hip_runtime.h>
#include <cstdint>
#include <cstddef>

#define IN_DIM 256
#define HID    512
#define TSTEPS 8
#define ROWS   16
#define NTHR   256     // 128 col-slots x 2 row-groups
#define RPT    8
#define KC8    48      // OpenBLAS kc=384 boundary in 8-k units
#define KC4    96      // kc=384 boundary in floats/4 (head loops)

// ---- pack: Pf[(k*128+jj)*4 + c] = W[jj+128c][k]  (LDS-tiled, coalesced reads)
__global__ void wpack4(const float* __restrict__ W, float* __restrict__ Pf, int K) {
  __shared__ float tl[32][33];
  const int k0 = blockIdx.x * 32;
  const int j0 = blockIdx.y * 32;            // j in [0,512)
  const int tx = threadIdx.x & 31, ty = threadIdx.x >> 5;   // 32x8
#pragma unroll
  for (int i = 0; i < 32; i += 8)
    tl[ty + i][tx] = W[(size_t)(j0 + ty + i) * K + (k0 + tx)];
  __syncthreads();
  const int c = j0 >> 7;
  const int jjb = j0 & 127;
#pragma unroll
  for (int i = 0; i < 32; i += 8) {
    int k = k0 + ty + i;
    Pf[((size_t)k * 128 + (jjb + tx)) * 4 + c] = tl[tx][ty + i];
  }
}

// ---- u8-spike GEMM core (layers 2/3): ascending-k fp32 fma chain, BLAS GEBP
// order (bit-identical: spike in {0,1} -> cvt_f32_ubyte exact). Per i8 per
// thread: 8 ds_read_b64 (broadcast) + 8 coalesced dwordx4 + 256 fma + 64 cvt.
__device__ __forceinline__ void gemm_u8(const unsigned char* __restrict__ spk,
                                        int rbase, const float4* __restrict__ P,
                                        int j1, int i8b, int i8e,
                                        float (&A)[RPT][4]) {
  for (int i8 = i8b; i8 < i8e; ++i8) {
    const float4* wp = P + ((size_t)i8 * 8) * 128 + j1;
    float4 w0 = wp[0],     w1 = wp[128],   w2 = wp[256],   w3 = wp[384];
    float4 w4 = wp[512],   w5 = wp[640],   w6 = wp[768],   w7 = wp[896];
#pragma unroll
    for (int r = 0; r < RPT; ++r) {
      uint2 sb = *reinterpret_cast<const uint2*>(spk + ((rbase + r) << 9) + (i8 << 3));
      float f0 = (float)(sb.x & 0xffu);
      float f1 = (float)((sb.x >> 8) & 0xffu);
      float f2 = (float)((sb.x >> 16) & 0xffu);
      float f3 = (float)(sb.x >> 24);
      float f4 = (float)(sb.y & 0xffu);
      float f5 = (float)((sb.y >> 8) & 0xffu);
      float f6 = (float)((sb.y >> 16) & 0xffu);
      float f7 = (float)(sb.y >> 24);
      float a0 = A[r][0], a1 = A[r][1], a2 = A[r][2], a3 = A[r][3];
      a0 = fmaf(f0, w0.x, a0); a1 = fmaf(f0, w0.y, a1); a2 = fmaf(f0, w0.z, a2); a3 = fmaf(f0, w0.w, a3);
      a0 = fmaf(f1, w1.x, a0); a1 = fmaf(f1, w1.y, a1); a2 = fmaf(f1, w1.z, a2); a3 = fmaf(f1, w1.w, a3);
      a0 = fmaf(f2, w2.x, a0); a1 = fmaf(f2, w2.y, a1); a2 = fmaf(f2, w2.z, a2); a3 = fmaf(f2, w2.w, a3);
      a0 = fmaf(f3, w3.x, a0); a1 = fmaf(f3, w3.y, a1); a2 = fmaf(f3, w3.z, a2); a3 = fmaf(f3, w3.w, a3);
      a0 = fmaf(f4, w4.x, a0); a1 = fmaf(f4, w4.y, a1); a2 = fmaf(f4, w4.z, a2); a3 = fmaf(f4, w4.w, a3);
      a0 = fmaf(f5, w5.x, a0); a1 = fmaf(f5, w5.y, a1); a2 = fmaf(f5, w5.z, a2); a3 = fmaf(f5, w5.w, a3);
      a0 = fmaf(f6, w6.x, a0); a1 = fmaf(f6, w6.y, a1); a2 = fmaf(f6, w6.z, a2); a3 = fmaf(f6, w6.w, a3);
      a0 = fmaf(f7, w7.x, a0); a1 = fmaf(f7, w7.y, a1); a2 = fmaf(f7, w7.z, a2); a3 = fmaf(f7, w7.w, a3);
      A[r][0] = a0; A[r][1] = a1; A[r][2] = a2; A[r][3] = a3;
    }
  }
}

// ---- f32-obs GEMM core (layer 1, K=256 single panel)
__device__ __forceinline__ void gemm_obs(const float* __restrict__ obsT,
                                         int rbase, const float4* __restrict__ P,
                                         int j1, float (&A)[RPT][4]) {
  for (int i4 = 0; i4 < IN_DIM / 4; ++i4) {
    const float4* wp = P + ((size_t)i4 * 4) * 128 + j1;
    float4 w0 = wp[0], w1 = wp[128], w2 = wp[256], w3 = wp[384];
#pragma unroll
    for (int r = 0; r < RPT; ++r) {
      float4 o = *reinterpret_cast<const float4*>(obsT + ((rbase + r) << 8) + (i4 << 2));
      float a0 = A[r][0], a1 = A[r][1], a2 = A[r][2], a3 = A[r][3];
      a0 = fmaf(o.x, w0.x, a0); a1 = fmaf(o.x, w0.y, a1); a2 = fmaf(o.x, w0.z, a2); a3 = fmaf(o.x, w0.w, a3);
      a0 = fmaf(o.y, w1.x, a0); a1 = fmaf(o.y, w1.y, a1); a2 = fmaf(o.y, w1.z, a2); a3 = fmaf(o.y, w1.w, a3);
      a0 = fmaf(o.z, w2.x, a0); a1 = fmaf(o.z, w2.y, a1); a2 = fmaf(o.z, w2.z, a2); a3 = fmaf(o.z, w2.w, a3);
      a0 = fmaf(o.w, w3.x, a0); a1 = fmaf(o.w, w3.y, a1); a2 = fmaf(o.w, w3.z, a2); a3 = fmaf(o.w, w3.w, a3);
      A[r][0] = a0; A[r][1] = a1; A[r][2] = a2; A[r][3] = a3;
    }
  }
}

__launch_bounds__(NTHR, 2)
__global__ void snn_net(const float* __restrict__ obs,
                        const float4* __restrict__ pP1, const float* __restrict__ pb1_,
                        const float4* __restrict__ pP2, const float* __restrict__ pb2_,
                        const float4* __restrict__ pP3, const float* __restrict__ pb3_,
                        const float* __restrict__ paw, const float* __restrict__ pab,
                        const float4* __restrict__ vP1, const float* __restrict__ vb1_,
                        const float4* __restrict__ vP2, const float* __restrict__ vb2_,
                        const float4* __restrict__ vP3, const float* __restrict__ vb3_,
                        const float* __restrict__ vhw, const float* __restrict__ vhb,
                        const float* __restrict__ log_std,
                        float* __restrict__ out, int B) {
  // XCD split: policy on XCD 0-3, value on 4-7 (each XCD L2 holds one net).
  const int bid = blockIdx.x;
  const int xcd = bid & 7;
  const int is_value = xcd >> 2;
  const int tile = (bid >> 3) * 4 + (xcd & 3);
  const float4* P1 = is_value ? vP1 : pP1;  const float* b1 = is_value ? vb1_ : pb1_;
  const float4* P2 = is_value ? vP2 : pP2;  const float* b2 = is_value ? vb2_ : pb2_;
  const float4* P3 = is_value ? vP3 : pP3;  const float* b3 = is_value ? vb3_ : pb3_;
  const float* Wh  = is_value ? vhw : paw;  const float* bh = is_value ? vhb : pab;

  // LDS 64KB: obsT f32 [0,16K); c1 packed f32 [16K,48K); spkA u8 [48K,56K);
  // spkB u8 [56K,64K). meanT f32 [0,32K) aliases obsT+c1-low after t-loop.
  __shared__ __align__(16) unsigned char lraw[65536];
  float* obsT = (float*)lraw;
  float4* c1p = (float4*)(lraw + 16384);          // [(row*128+j1)] float4 (4 cols)
  unsigned char* spkA = lraw + 49152;
  unsigned char* spkB = lraw + 57344;
  float* meanT = (float*)lraw;

  const int tid = threadIdx.x;
  const int j1 = tid & 127;
  const int rbase = (tid >> 7) * RPT;   // 0 or 8
  const int r0 = tile * ROWS;

  // ---- stage obs tile (coalesced float4)
  {
    const float4* src = reinterpret_cast<const float4*>(obs + (size_t)r0 * IN_DIM);
    float4* dst = reinterpret_cast<float4*>(obsT);
    for (int e = tid; e < ROWS * IN_DIM / 4; e += NTHR) dst[e] = src[e];
  }
  __syncthreads();

  // ---- layer-1 currents (K=256 single BLAS panel; bias AFTER sum) -> LDS
  {
    float Sa[RPT][4];
#pragma unroll
    for (int r = 0; r < RPT; ++r)
#pragma unroll
      for (int c = 0; c < 4; ++c) Sa[r][c] = 0.f;
    gemm_obs(obsT, rbase, P1, j1, Sa);
    const float bb0 = b1[j1], bb1 = b1[j1 + 128], bb2 = b1[j1 + 256], bb3 = b1[j1 + 384];
#pragma unroll
    for (int r = 0; r < RPT; ++r) {
      float4 v;
      v.x = __fadd_rn(Sa[r][0], bb0);
      v.y = __fadd_rn(Sa[r][1], bb1);
      v.z = __fadd_rn(Sa[r][2], bb2);
      v.w = __fadd_rn(Sa[r][3], bb3);
      c1p[(rbase + r) * 128 + j1] = v;
    }
  }
  __syncthreads();

  // ---- fp32 membranes (registers); layer-3 spike counts packed 4b fields
  float m1[RPT][4], m2[RPT][4], m3[RPT][4];
  unsigned cnt32[4] = {0u, 0u, 0u, 0u};   // field (r,c): word r>>1, nibble (r&1)*4+c
#pragma unroll
  for (int r = 0; r < RPT; ++r)
#pragma unroll
    for (int c = 0; c < 4; ++c) { m1[r][c] = 0.f; m2[r][c] = 0.f; m3[r][c] = 0.f; }

  const float bias2[4] = { b2[j1], b2[j1 + 128], b2[j1 + 256], b2[j1 + 384] };
  const float bias3[4] = { b3[j1], b3[j1 + 128], b3[j1 + 256], b3[j1 + 384] };

  for (int t = 0; t < TSTEPS; ++t) {
    // ---- LIF layer 1: m = RN(RN(0.95*m)+cur); spike u8 {0,1} -> spkA
#pragma unroll
    for (int r = 0; r < RPT; ++r) {
      float4 cur = c1p[(rbase + r) * 128 + j1];
      float cc[4] = { cur.x, cur.y, cur.z, cur.w };
#pragma unroll
      for (int c = 0; c < 4; ++c) {
        m1[r][c] = __fadd_rn(__fmul_rn(0.95f, m1[r][c]), cc[c]);
        bool f = m1[r][c] > 1.0f;
        m1[r][c] = __fsub_rn(m1[r][c], f ? 1.0f : 0.0f);
        spkA[((rbase + r) << 9) + j1 + (c << 7)] = f ? 1 : 0;
      }
    }
    __syncthreads();   // A ready; also fences gemm3(t-1) B-reads before LIF2 B-writes

    // ---- layer 2: two BLAS panels (kc=384), RN(S0+S1), then +bias
    float S0[RPT][4], S1[RPT][4];
#pragma unroll
    for (int r = 0; r < RPT; ++r)
#pragma unroll
      for (int c = 0; c < 4; ++c) { S0[r][c] = 0.f; S1[r][c] = 0.f; }
    gemm_u8(spkA, rbase, P2, j1, 0, KC8, S0);
    gemm_u8(spkA, rbase, P2, j1, KC8, HID >> 3, S1);
#pragma unroll
    for (int r = 0; r < RPT; ++r) {
#pragma unroll
      for (int c = 0; c < 4; ++c) {
        float cur = __fadd_rn(__fadd_rn(S0[r][c], S1[r][c]), bias2[c]);
        m2[r][c] = __fadd_rn(__fmul_rn(0.95f, m2[r][c]), cur);
        bool f = m2[r][c] > 1.0f;
        m2[r][c] = __fsub_rn(m2[r][c], f ? 1.0f : 0.0f);
        spkB[((rbase + r) << 9) + j1 + (c << 7)] = f ? 1 : 0;
      }
    }
    __syncthreads();   // B ready; gemm2 A-reads done before next LIF1 A-writes

    // ---- layer 3: same structure; packed spike counts
#pragma unroll
    for (int r = 0; r < RPT; ++r)
#pragma unroll
      for (int c = 0; c < 4; ++c) { S0[r][c] = 0.f; S1[r][c] = 0.f; }
    gemm_u8(spkB, rbase, P3, j1, 0, KC8, S0);
    gemm_u8(spkB, rbase, P3, j1, KC8, HID >> 3, S1);
#pragma unroll
    for (int r = 0; r < RPT; ++r) {
#pragma unroll
      for (int c = 0; c < 4; ++c) {
        float cur = __fadd_rn(__fadd_rn(S0[r][c], S1[r][c]), bias3[c]);
        m3[r][c] = __fadd_rn(__fmul_rn(0.95f, m3[r][c]), cur);
        bool f = m3[r][c] > 1.0f;
        m3[r][c] = __fsub_rn(m3[r][c], f ? 1.0f : 0.0f);
        cnt32[r >> 1] += f ? (1u << (((r & 1) * 4 + c) * 4)) : 0u;
      }
    }
    // no barrier: next LIF1 writes spkA only; fenced by the barrier after it.
  }
  __syncthreads();   // all t-loop LDS traffic done before meanT overwrites

  // ---- mean spikes (count/8 exact) into f32 tile [row][col]
#pragma unroll
  for (int r = 0; r < RPT; ++r)
#pragma unroll
    for (int c = 0; c < 4; ++c)
      meanT[(rbase + r) * HID + j1 + (c << 7)] =
          (float)((cnt32[r >> 1] >> (((r & 1) * 4 + c) * 4)) & 15u) * 0.125f;
  __syncthreads();

  // ---- heads (BLAS two-panel structure, kc=384)
  if (is_value == 0) {
    if (tid < ROWS * 6) {
      int r = tid / 6, k = tid % 6;
      const float* wr = Wh + (size_t)k * HID;
      float S0h = 0.f, S1h = 0.f;
      for (int i = 0; i < 4 * KC4; ++i)   S0h = fmaf(meanT[r * HID + i], wr[i], S0h);
      for (int i = 4 * KC4; i < HID; ++i) S1h = fmaf(meanT[r * HID + i], wr[i], S1h);
      out[(size_t)(r0 + r) * 6 + k] = __fadd_rn(__fadd_rn(S0h, S1h), bh[k]);
      out[(size_t)B * 6 + (size_t)(r0 + r) * 6 + k] = log_std[k];
    }
  } else {
    if (tid < ROWS) {
      int r = tid;
      float S0h = 0.f, S1h = 0.f;
      for (int i = 0; i < 4 * KC4; ++i)   S0h = fmaf(meanT[r * HID + i], Wh[i], S0h);
      for (int i = 4 * KC4; i < HID; ++i) S1h = fmaf(meanT[r * HID + i], Wh[i], S1h);
      out[(size_t)B * 12 + (size_t)(r0 + r)] = __fadd_rn(__fadd_rn(S0h, S1h), bh[0]);
    }
  }
}

// ---------------- fallback (round-3 kernel, proven; used if ws too small) --------
#define NTHRB 512
#define RPTB  8
template<int PITCH4>
__device__ __forceinline__ void gemm_f32(const float* __restrict__ sl, int rbase,
                                         const float4* __restrict__ wra,
                                         const float4* __restrict__ wrb,
                                         int i4begin, int i4end,
                                         float a0[RPTB], float a1[RPTB]) {
  const float4* slv = reinterpret_cast<const float4*>(sl);
  for (int i4 = i4begin; i4 < i4end; ++i4) {
    float4 wa = wra[i4];
    float4 wb = wrb[i4];
#pragma unroll
    for (int r = 0; r < RPTB; ++r) {
      float4 s = slv[(rbase + r) * PITCH4 + i4];
      a0[r] = fmaf(s.w, wa.w, fmaf(s.z, wa.z, fmaf(s.y, wa.y, fmaf(s.x, wa.x, a0[r]))));
      a1[r] = fmaf(s.w, wb.w, fmaf(s.z, wb.z, fmaf(s.y, wb.y, fmaf(s.x, wb.x, a1[r]))));
    }
  }
}

__launch_bounds__(NTHRB, 2)
__global__ void snn_net_base(const float* __restrict__ obs,
                             const float* __restrict__ pW1, const float* __restrict__ pb1_,
                             const float* __restrict__ pW2, const float* __restrict__ pb2_,
                             const float* __restrict__ pW3, const float* __restrict__ pb3_,
                             const float* __restrict__ paw, const float* __restrict__ pab,
                             const float* __restrict__ vW1, const float* __restrict__ vb1_,
                             const float* __restrict__ vW2, const float* __restrict__ vb2_,
                             const float* __restrict__ vW3, const float* __restrict__ vb3_,
                             const float* __restrict__ vhw, const float* __restrict__ vhb,
                             const float* __restrict__ log_std,
                             float* __restrict__ out, int B) {
  const int is_value = blockIdx.y;
  const float* W1 = is_value ? vW1 : pW1;  const float* b1 = is_value ? vb1_ : pb1_;
  const float* W2 = is_value ? vW2 : pW2;  const float* b2 = is_value ? vb2_ : pb2_;
  const float* W3 = is_value ? vW3 : pW3;  const float* b3 = is_value ? vb3_ : pb3_;
  const float* Wh = is_value ? vhw : paw;  const float* bh = is_value ? vhb : pab;

  __shared__ float sl[ROWS * HID];
  const int tid = threadIdx.x;
  const int r0 = blockIdx.x * ROWS;
  const int j1 = tid & 255, j2 = j1 + 256;
  const int rbase = (tid >> 8) * RPTB;

  for (int e = tid; e < ROWS * IN_DIM; e += NTHRB)
    sl[e] = obs[(size_t)r0 * IN_DIM + e];
  __syncthreads();

  float c1a[RPTB], c1b[RPTB];
  {
    float Sa[RPTB], Sb[RPTB];
#pragma unroll
    for (int r = 0; r < RPTB; ++r) { Sa[r] = 0.f; Sb[r] = 0.f; }
    gemm_f32<IN_DIM / 4>(sl, rbase,
        reinterpret_cast<const float4*>(W1 + (size_t)j1 * IN_DIM),
        reinterpret_cast<const float4*>(W1 + (size_t)j2 * IN_DIM),
        0, IN_DIM / 4, Sa, Sb);
    const float ba = b1[j1], bb = b1[j2];
#pragma unroll
    for (int r = 0; r < RPTB; ++r) {
      c1a[r] = __fadd_rn(Sa[r], ba);
      c1b[r] = __fadd_rn(Sb[r], bb);
    }
  }
  __syncthreads();

  float m1a[RPTB], m1b[RPTB], m2a[RPTB], m2b[RPTB], m3a[RPTB], m3b[RPTB];
  float sca[RPTB], scb[RPTB];
#pragma unroll
  for (int r = 0; r < RPTB; ++r) {
    m1a[r] = 0.f; m1b[r] = 0.f; m2a[r] = 0.f; m2b[r] = 0.f;
    m3a[r] = 0.f; m3b[r] = 0.f; sca[r] = 0.f; scb[r] = 0.f;
  }

  const float4* w2a = reinterpret_cast<const float4*>(W2 + (size_t)j1 * HID);
  const float4* w2b = reinterpret_cast<const float4*>(W2 + (size_t)j2 * HID);
  const float4* w3a = reinterpret_cast<const float4*>(W3 + (size_t)j1 * HID);
  const float4* w3b = reinterpret_cast<const float4*>(W3 + (size_t)j2 * HID);
  const float bias2a = b2[j1], bias2b = b2[j2];
  const float bias3a = b3[j1], bias3b = b3[j2];

  for (int t = 0; t < TSTEPS; ++t) {
#pragma unroll
    for (int r = 0; r < RPTB; ++r) {
      m1a[r] = __fadd_rn(__fmul_rn(0.95f, m1a[r]), c1a[r]);
      float sa = (m1a[r] > 1.0f) ? 1.0f : 0.0f;
      m1a[r] = __fsub_rn(m1a[r], sa);
      sl[(rbase + r) * HID + j1] = sa;
      m1b[r] = __fadd_rn(__fmul_rn(0.95f, m1b[r]), c1b[r]);
      float sb = (m1b[r] > 1.0f) ? 1.0f : 0.0f;
      m1b[r] = __fsub_rn(m1b[r], sb);
      sl[(rbase + r) * HID + j2] = sb;
    }
    __syncthreads();

    float S0a[RPTB], S0b[RPTB], S1a[RPTB], S1b[RPTB];
#pragma unroll
    for (int r = 0; r < RPTB; ++r) { S0a[r] = 0.f; S0b[r] = 0.f; S1a[r] = 0.f; S1b[r] = 0.f; }
    gemm_f32<HID / 4>(sl, rbase, w2a, w2b, 0, KC4, S0a, S0b);
    gemm_f32<HID / 4>(sl, rbase, w2a, w2b, KC4, HID / 4, S1a, S1b);
    __syncthreads();
#pragma unroll
    for (int r = 0; r < RPTB; ++r) {
      float cura = __fadd_rn(__fadd_rn(S0a[r], S1a[r]), bias2a);
      float curb = __fadd_rn(__fadd_rn(S0b[r], S1b[r]), bias2b);
      m2a[r] = __fadd_rn(__fmul_rn(0.95f, m2a[r]), cura);
      float sa = (m2a[r] > 1.0f) ? 1.0f : 0.0f;
      m2a[r] = __fsub_rn(m2a[r], sa);
      sl[(rbase + r) * HID + j1] = sa;
      m2b[r] = __fadd_rn(__fmul_rn(0.95f, m2b[r]), curb);
      float sb = (m2b[r] > 1.0f) ? 1.0f : 0.0f;
      m2b[r] = __fsub_rn(m2b[r], sb);
      sl[(rbase + r) * HID + j2] = sb;
    }
    __syncthreads();

#pragma unroll
    for (int r = 0; r < RPTB; ++r) { S0a[r] = 0.f; S0b[r] = 0.f; S1a[r] = 0.f; S1b[r] = 0.f; }
    gemm_f32<HID / 4>(sl, rbase, w3a, w3b, 0, KC4, S0a, S0b);
    gemm_f32<HID / 4>(sl, rbase, w3a, w3b, KC4, HID / 4, S1a, S1b);
    __syncthreads();
#pragma unroll
    for (int r = 0; r < RPTB; ++r) {
      float cura = __fadd_rn(__fadd_rn(S0a[r], S1a[r]), bias3a);
      float curb = __fadd_rn(__fadd_rn(S0b[r], S1b[r]), bias3b);
      m3a[r] = __fadd_rn(__fmul_rn(0.95f, m3a[r]), cura);
      float sa = (m3a[r] > 1.0f) ? 1.0f : 0.0f;
      m3a[r] = __fsub_rn(m3a[r], sa);
      sca[r] = __fadd_rn(sca[r], sa);
      m3b[r] = __fadd_rn(__fmul_rn(0.95f, m3b[r]), curb);
      float sb = (m3b[r] > 1.0f) ? 1.0f : 0.0f;
      m3b[r] = __fsub_rn(m3b[r], sb);
      scb[r] = __fadd_rn(scb[r], sb);
    }
  }

#pragma unroll
  for (int r = 0; r < RPTB; ++r) {
    sl[(rbase + r) * HID + j1] = sca[r] * 0.125f;
    sl[(rbase + r) * HID + j2] = scb[r] * 0.125f;
  }
  __syncthreads();

  if (is_value == 0) {
    if (tid < ROWS * 6) {
      int r = tid / 6, k = tid % 6;
      const float* wr = Wh + (size_t)k * HID;
      float S0 = 0.f, S1 = 0.f;
      for (int i = 0; i < 4 * KC4; ++i)   S0 = fmaf(sl[r * HID + i], wr[i], S0);
      for (int i = 4 * KC4; i < HID; ++i) S1 = fmaf(sl[r * HID + i], wr[i], S1);
      out[(size_t)(r0 + r) * 6 + k] = __fadd_rn(__fadd_rn(S0, S1), bh[k]);
      out[(size_t)B * 6 + (size_t)(r0 + r) * 6 + k] = log_std[k];
    }
  } else {
    if (tid < ROWS) {
      int r = tid;
      float S0 = 0.f, S1 = 0.f;
      for (int i = 0; i < 4 * KC4; ++i)   S0 = fmaf(sl[r * HID + i], Wh[i], S0);
      for (int i = 4 * KC4; i < HID; ++i) S1 = fmaf(sl[r * HID + i], Wh[i], S1);
      out[(size_t)B * 12 + (size_t)(r0 + r)] = __fadd_rn(__fadd_rn(S0, S1), bh[0]);
    }
  }
}

extern "C" void kernel_launch(void* const* d_in, const int* in_sizes, int n_in,
                              void* d_out, int out_size, void* d_ws, size_t ws_size,
                              hipStream_t stream) {
  const float* obs = (const float*)d_in[0];
  const float* pw1 = (const float*)d_in[1];  const float* pb1 = (const float*)d_in[2];
  const float* pw2 = (const float*)d_in[3];  const float* pb2 = (const float*)d_in[4];
  const float* pw3 = (const float*)d_in[5];  const float* pb3 = (const float*)d_in[6];
  const float* aw  = (const float*)d_in[7];  const float* ab  = (const float*)d_in[8];
  const float* vw1 = (const float*)d_in[9];  const float* vb1 = (const float*)d_in[10];
  const float* vw2 = (const float*)d_in[11]; const float* vb2 = (const float*)d_in[12];
  const float* vw3 = (const float*)d_in[13]; const float* vb3 = (const float*)d_in[14];
  const float* hw  = (const float*)d_in[15]; const float* hb  = (const float*)d_in[16];
  const float* lsd = (const float*)d_in[17];
  float* out = (float*)d_out;

  const int B  = in_sizes[0] / IN_DIM;
  const int nb = B / ROWS;

  const size_t need = (size_t)(IN_DIM * HID + 2 * HID * HID) * 2 * sizeof(float);
  if (ws_size >= need && (nb & 3) == 0) {
    float* w = (float*)d_ws;
    float* pP1 = w;
    float* pP2 = w + 131072;
    float* pP3 = w + 393216;
    float* vP1 = w + 655360;
    float* vP2 = w + 786432;
    float* vP3 = w + 1048576;
    wpack4<<<dim3(IN_DIM / 32, 16), 256, 0, stream>>>(pw1, pP1, IN_DIM);
    wpack4<<<dim3(HID / 32, 16),    256, 0, stream>>>(pw2, pP2, HID);
    wpack4<<<dim3(HID / 32, 16),    256, 0, stream>>>(pw3, pP3, HID);
    wpack4<<<dim3(IN_DIM / 32, 16), 256, 0, stream>>>(vw1, vP1, IN_DIM);
    wpack4<<<dim3(HID / 32, 16),    256, 0, stream>>>(vw2, vP2, HID);
    wpack4<<<dim3(HID / 32, 16),    256, 0, stream>>>(vw3, vP3, HID);
    snn_net<<<2 * nb, NTHR, 0, stream>>>(obs,
        (const float4*)pP1, pb1, (const float4*)pP2, pb2, (const float4*)pP3, pb3, aw, ab,
        (const float4*)vP1, vb1, (const float4*)vP2, vb2, (const float4*)vP3, vb3, hw, hb,
        lsd, out, B);
  } else {
    dim3 grid(nb, 2);
    snn_net_base<<<grid, NTHRB, 0, stream>>>(obs,
        pw1, pb1, pw2, pb2, pw3, pb3, aw, ab,
        vw1, vb1, vw2, vb2, vw3, vb3, hw, hb,
        lsd, out, B);
  }
}